// Round 9
// baseline (355.459 us; speedup 1.0000x reference)
//
#include <hip/hip_runtime.h>

// R9: occupancy + repack fix.
//  - block = 512 threads (8 waves) sharing ONE 71,744 B LDS slab -> 8 waves/CU
//    (2 waves/SIMD) guaranteed even at 1 block/CU. R7/R8 ran 1 wave/SIMD
//    (Occupancy ~11%): 79 KB slab x 2 blocks didn't co-schedule.
//  - slab shrunk by compact L1/L4 frags (only 16/64 lanes nonzero; other
//    lanes read a shared 2 KB zero region via lane-conditional base).
//  - pkrelu: cvt_pk_bf16_f32 if present, else relu + (+0x8000) + v_perm_b32
//    (round-half-away, same 0.5-ulp bound as RNE) -> <=5 VALU per packed u32.
//  - T=4 row-tiles/wave-iter kept (halves LDS weight streaming vs T=2).
//
// LDS/ws layout (bytes):
//   0     : W2 frags, 32 x 1024   (f = ks*8+nt; lane l at f*1024 + l*16)
//   32768 : W3 frags, 32 x 1024
//   65536 : L1 compact, 8 x 256   (frag nt, slot n(=row m), 16B short8:
//           j<6 -> W1[(nt*16+n)*6+j], j==6 -> b1[nt*16+n], j==7 -> 0)
//   67584 : L4 compact, 4 x 256   (frag ks, slot s=q*4+n(out row), 16B:
//           W4[n*128 + sig_inv(ks*32+q*8+j)])
//   68608 : zeros, 2048
//   70656 : bias2 = b2[0..127]    (f32x4 entry nt*4+q)
//   71168 : bias3 = b3[0..127]
//   71680 : b4 padded (q==0 -> b4[0..3], else 0)
//   total 71744

typedef __attribute__((ext_vector_type(8))) short short8;
typedef __attribute__((ext_vector_type(4))) float f32x4;
typedef __attribute__((ext_vector_type(2))) float f32x2;
typedef __attribute__((ext_vector_type(4))) unsigned int u32x4;

#define MFMA(a, b, c) __builtin_amdgcn_mfma_f32_16x16x32_bf16((a), (b), (c), 0, 0, 0)

__device__ __forceinline__ unsigned short bfr(float f) {  // fp32->bf16 RNE
  unsigned u = __builtin_bit_cast(unsigned, f);
  u += 0x7FFFu + ((u >> 16) & 1u);
  return (unsigned short)(u >> 16);
}

__device__ __forceinline__ unsigned pkrelu(float a, float b) {
  a = __builtin_fmaxf(a, 0.f);
  b = __builtin_fmaxf(b, 0.f);
#if __has_builtin(__builtin_amdgcn_cvt_pk_bf16_f32)
  auto h = __builtin_amdgcn_cvt_pk_bf16_f32(a, b);
  return __builtin_bit_cast(unsigned, h);
#else
  // round-half-away bf16: same 0.5-ulp bound as RNE (ties are measure-zero)
  unsigned ia = __builtin_bit_cast(unsigned, a) + 0x8000u;
  unsigned ib = __builtin_bit_cast(unsigned, b) + 0x8000u;
#if __has_builtin(__builtin_amdgcn_perm)
  return __builtin_amdgcn_perm(ib, ia, 0x07060302u);  // (ia.hi16, ib.hi16)
#else
  return (ia >> 16) | (ib & 0xFFFF0000u);
#endif
#endif
}

__device__ __forceinline__ short8 pack4(const f32x4& a0, const f32x4& a1) {
  u32x4 u;
  u.x = pkrelu(a0.x, a0.y);
  u.y = pkrelu(a0.z, a0.w);
  u.z = pkrelu(a1.x, a1.y);
  u.w = pkrelu(a1.z, a1.w);
  return __builtin_bit_cast(short8, u);
}

// consumer B k-slot kp <- producer neuron slot sig_inv(kp)
__device__ __forceinline__ int sig_inv(int kp) {
  return ((kp >> 5) << 5) + (((kp >> 2) & 1) << 4) + (((kp >> 3) & 3) << 2) + (kp & 3);
}

__global__ void nerf_stage(const float* __restrict__ W1, const float* __restrict__ b1,
                           const float* __restrict__ W2, const float* __restrict__ b2,
                           const float* __restrict__ W3, const float* __restrict__ b3,
                           const float* __restrict__ W4, const float* __restrict__ b4,
                           void* __restrict__ ws) {
  unsigned short* wf = (unsigned short*)ws;
  const int idx = blockIdx.x * 256 + threadIdx.x;
  const int stride = gridDim.x * 256;

  // W2 (f 0..31) and W3 (f 32..63) full frags
  for (int p = idx; p < 64 * 64; p += stride) {
    const int f = p >> 6, l = p & 63, m = l & 15, q = l >> 4;
    const int g = f & 31, ks = g >> 3, nt = g & 7;
    const float* W = (f < 32) ? W2 : W3;
    unsigned short v[8];
#pragma unroll
    for (int j = 0; j < 8; ++j)
      v[j] = bfr(W[(nt * 16 + m) * 128 + sig_inv(ks * 32 + q * 8 + j)]);
#pragma unroll
    for (int j = 0; j < 8; ++j) wf[f * 512 + l * 8 + j] = v[j];
  }

  // L1 compact: 8 frags x 16 slots at byte 65536
  for (int e = idx; e < 128; e += stride) {
    const int nt = e >> 4, n = e & 15;
    unsigned short v[8];
#pragma unroll
    for (int j = 0; j < 8; ++j) {
      float val = 0.f;
      if (j < 6) val = W1[(nt * 16 + n) * 6 + j];
      else if (j == 6) val = b1[nt * 16 + n];
      v[j] = bfr(val);
    }
#pragma unroll
    for (int j = 0; j < 8; ++j) wf[(65536 >> 1) + e * 8 + j] = v[j];
  }

  // L4 compact: 4 frags x 16 slots (s = q*4 + outrow) at byte 67584
  for (int e = idx; e < 64; e += stride) {
    const int ks = e >> 4, s = e & 15, q = s >> 2, n = s & 3;
    unsigned short v[8];
#pragma unroll
    for (int j = 0; j < 8; ++j)
      v[j] = bfr(W4[n * 128 + sig_inv(ks * 32 + q * 8 + j)]);
#pragma unroll
    for (int j = 0; j < 8; ++j) wf[(67584 >> 1) + e * 8 + j] = v[j];
  }

  // zeros at byte 68608 (ws is poisoned 0xAA each launch -> must clear)
  {
    float* z = (float*)((char*)ws + 68608);
    for (int e = idx; e < 512; e += stride) z[e] = 0.f;
  }

  // biases at byte 70656: b2 | b3 | b4 padded
  {
    float* wb = (float*)((char*)ws + 70656);
    for (int e = idx; e < 272; e += stride) {
      float val;
      if (e < 128) val = b2[e];
      else if (e < 256) val = b3[e - 128];
      else val = ((e & 15) < 4) ? b4[e & 3] : 0.f;
      wb[e] = val;
    }
  }
}

__launch_bounds__(512)
__global__ void nerf_main(const float* __restrict__ x, float* __restrict__ out,
                          const void* __restrict__ ws, int nGroups) {
  __shared__ __align__(16) unsigned short lds[35872];  // 71744 B

  {  // copy the whole constant slab: 71744/16 = 4484 16B chunks
    const u32x4* src = (const u32x4*)ws;
    u32x4* dst = (u32x4*)lds;
    for (int i = threadIdx.x; i < 4484; i += 512) dst[i] = src[i];
  }
  __syncthreads();

  const int lane = threadIdx.x & 63;
  const int wid = threadIdx.x >> 6;
  const int q = lane >> 4;
  const int n = lane & 15;

  const int waveId = blockIdx.x * 8 + wid;
  const int totalWaves = gridDim.x * 8;

  // lane-conditional bases (computed once; frag index goes in the imm offset)
  const unsigned short* w2b = lds + lane * 8;            // + (ks*8+nt)*512
  const unsigned short* w3b = lds + 16384 + lane * 8;    // + (ks*8+nt)*512
  const unsigned short* l1b =
      lds + (((q == 0) ? 65536 : 68608) >> 1) + n * 8;   // + nt*128
  const unsigned short* l4b =
      lds + (((n < 4) ? (67584 + (q * 4 + n) * 16) : (68608 + n * 16)) >> 1);  // + ks*128
  const f32x4* bias2 = (const f32x4*)((const char*)lds + 70656) + q;  // + nt*4
  const f32x4* bias3 = (const f32x4*)((const char*)lds + 71168) + q;  // + nt*4
  const f32x4* b4p   = (const f32x4*)((const char*)lds + 71680) + q;

  const f32x4 zf = {0.f, 0.f, 0.f, 0.f};

  float px[4][6] = {};
  int g = waveId;
  if (g < nGroups && q == 0) {
#pragma unroll
    for (int t = 0; t < 4; ++t) {
      const float* p = x + (g * 64 + t * 16 + n) * 6;
      f32x2 a = *(const f32x2*)p, b = *(const f32x2*)(p + 2), c = *(const f32x2*)(p + 4);
      px[t][0] = a.x; px[t][1] = a.y; px[t][2] = b.x;
      px[t][3] = b.y; px[t][4] = c.x; px[t][5] = c.y;
    }
  }

  for (; g < nGroups; g += totalWaves) {
    // ---- x -> layer-1 B frags (q==0: k0..5 = x, k6 = 1.0 bias slot) ----
    short8 xb[4];
#pragma unroll
    for (int t = 0; t < 4; ++t) {
      short8 v = {0, 0, 0, 0, 0, 0, 0, 0};
      if (q == 0) {
        v[0] = (short)bfr(px[t][0]); v[1] = (short)bfr(px[t][1]);
        v[2] = (short)bfr(px[t][2]); v[3] = (short)bfr(px[t][3]);
        v[4] = (short)bfr(px[t][4]); v[5] = (short)bfr(px[t][5]);
        v[6] = (short)0x3F80;  // bf16 1.0
      }
      xb[t] = v;
    }
    const int gn = g + totalWaves;
    if (gn < nGroups && q == 0) {
#pragma unroll
      for (int t = 0; t < 4; ++t) {
        const float* p = x + (gn * 64 + t * 16 + n) * 6;
        f32x2 a = *(const f32x2*)p, b = *(const f32x2*)(p + 2), c = *(const f32x2*)(p + 4);
        px[t][0] = a.x; px[t][1] = a.y; px[t][2] = b.x;
        px[t][3] = b.y; px[t][4] = c.x; px[t][5] = c.y;
      }
    }

    short8 B1[4][4], B2[4][4];

    // ---- layer 1 (compact frags; bias in k-slot 6; C = 0) ----
#pragma unroll
    for (int ntp = 0; ntp < 4; ++ntp) {
      const short8 w0 = *(const short8*)(l1b + (2 * ntp) * 128);
      const short8 w1 = *(const short8*)(l1b + (2 * ntp + 1) * 128);
      f32x4 a0[4], a1[4];
#pragma unroll
      for (int t = 0; t < 4; ++t) {
        a0[t] = MFMA(w0, xb[t], zf);
        a1[t] = MFMA(w1, xb[t], zf);
      }
#pragma unroll
      for (int t = 0; t < 4; ++t) B1[t][ntp] = pack4(a0[t], a1[t]);
    }

    // ---- layer 2 (W2 frags; bias as C at ks==0) ----
#pragma unroll
    for (int ntp = 0; ntp < 4; ++ntp) {
      f32x4 a0[4], a1[4];
#pragma unroll
      for (int ks = 0; ks < 4; ++ks) {
        const short8 w0 = *(const short8*)(w2b + (ks * 8 + 2 * ntp) * 512);
        const short8 w1 = *(const short8*)(w2b + (ks * 8 + 2 * ntp + 1) * 512);
        if (ks == 0) {
          const f32x4 bv0 = bias2[(2 * ntp) * 4];
          const f32x4 bv1 = bias2[(2 * ntp + 1) * 4];
#pragma unroll
          for (int t = 0; t < 4; ++t) {
            a0[t] = MFMA(w0, B1[t][0], bv0);
            a1[t] = MFMA(w1, B1[t][0], bv1);
          }
        } else {
#pragma unroll
          for (int t = 0; t < 4; ++t) {
            a0[t] = MFMA(w0, B1[t][ks], a0[t]);
            a1[t] = MFMA(w1, B1[t][ks], a1[t]);
          }
        }
      }
#pragma unroll
      for (int t = 0; t < 4; ++t) B2[t][ntp] = pack4(a0[t], a1[t]);
    }

    // ---- layer 3 (W3 frags) ----
#pragma unroll
    for (int ntp = 0; ntp < 4; ++ntp) {
      f32x4 a0[4], a1[4];
#pragma unroll
      for (int ks = 0; ks < 4; ++ks) {
        const short8 w0 = *(const short8*)(w3b + (ks * 8 + 2 * ntp) * 512);
        const short8 w1 = *(const short8*)(w3b + (ks * 8 + 2 * ntp + 1) * 512);
        if (ks == 0) {
          const f32x4 bv0 = bias3[(2 * ntp) * 4];
          const f32x4 bv1 = bias3[(2 * ntp + 1) * 4];
#pragma unroll
          for (int t = 0; t < 4; ++t) {
            a0[t] = MFMA(w0, B2[t][0], bv0);
            a1[t] = MFMA(w1, B2[t][0], bv1);
          }
        } else {
#pragma unroll
          for (int t = 0; t < 4; ++t) {
            a0[t] = MFMA(w0, B2[t][ks], a0[t]);
            a1[t] = MFMA(w1, B2[t][ks], a1[t]);
          }
        }
      }
#pragma unroll
      for (int t = 0; t < 4; ++t) B1[t][ntp] = pack4(a0[t], a1[t]);  // reuse B1
    }

    // ---- layer 4 (compact frags; out rows at q==0) ----
    f32x4 o[4];
    {
      const f32x4 bv = b4p[0];
#pragma unroll
      for (int ks = 0; ks < 4; ++ks) {
        const short8 w = *(const short8*)(l4b + ks * 128);
        if (ks == 0) {
#pragma unroll
          for (int t = 0; t < 4; ++t) o[t] = MFMA(w, B1[t][0], bv);
        } else {
#pragma unroll
          for (int t = 0; t < 4; ++t) o[t] = MFMA(w, B1[t][ks], o[t]);
        }
      }
    }
    if (q == 0) {
#pragma unroll
      for (int t = 0; t < 4; ++t)
        *(f32x4*)(out + (g * 64 + t * 16 + n) * 4) = o[t];
    }
  }
}

extern "C" void kernel_launch(void* const* d_in, const int* in_sizes, int n_in,
                              void* d_out, int out_size, void* d_ws, size_t ws_size,
                              hipStream_t stream) {
  const float* x  = (const float*)d_in[0];
  const float* W1 = (const float*)d_in[1];
  const float* b1 = (const float*)d_in[2];
  const float* W2 = (const float*)d_in[3];
  const float* b2 = (const float*)d_in[4];
  const float* W3 = (const float*)d_in[5];
  const float* b3 = (const float*)d_in[6];
  const float* W4 = (const float*)d_in[7];
  const float* b4 = (const float*)d_in[8];
  float* out = (float*)d_out;

  const int N = in_sizes[0] / 6;
  const int nGroups = N / 64;  // 4 tiles of 16 rows per wave-iteration -> 16384

  nerf_stage<<<dim3(4), dim3(256), 0, stream>>>(W1, b1, W2, b2, W3, b3, W4, b4, d_ws);

  // 256 blocks x 8 waves = 2048 waves; 1 block/CU, 8 waves/CU (2/SIMD), 8 iters
  nerf_main<<<dim3(256), dim3(512), 0, stream>>>(x, out, d_ws, nGroups);
}

// Round 10
// 189.986 us; speedup vs baseline: 1.8710x; 1.8710x over previous
//
#include <hip/hip_runtime.h>

// R10 = R7 body (T=2, block=256 -> allocator's 256-reg tier, spill-free)
//     + R9 compact 71,744 B slab (-> 2 blocks/CU = 2 waves/SIMD)
//     + R9 perm-based pkrelu.
// Single effective variable vs R7: blocks/CU 1 -> 2. R7 ran 1 wave/SIMD
// (Occupancy 11%, 79 KB slab didn't co-schedule), so MFMA/VALU/LDS pipes
// serialized; 2 waves/SIMD lets them co-issue (wall -> max, not sum).
//
// LDS/ws layout (bytes):
//   0     : W2 frags, 32 x 1024   (f = ks*8+nt; lane l at f*1024 + l*16)
//   32768 : W3 frags, 32 x 1024
//   65536 : L1 compact, 8 x 256   (frag nt, slot n: j<6 -> W1[(nt*16+n)*6+j],
//                                  j==6 -> b1[nt*16+n], j==7 -> 0)
//   67584 : L4 compact, 4 x 256   (frag ks, slot s=q*4+outrow)
//   68608 : zeros, 2048
//   70656 : bias2 = b2[0..127]    (f32x4 entry nt*4+q)
//   71168 : bias3 = b3[0..127]
//   71680 : b4 padded (q==0 -> b4[0..3], else 0)
//   total 71744

typedef __attribute__((ext_vector_type(8))) short short8;
typedef __attribute__((ext_vector_type(4))) float f32x4;
typedef __attribute__((ext_vector_type(2))) float f32x2;
typedef __attribute__((ext_vector_type(4))) unsigned int u32x4;

#define MFMA(a, b, c) __builtin_amdgcn_mfma_f32_16x16x32_bf16((a), (b), (c), 0, 0, 0)

__device__ __forceinline__ unsigned short bfr(float f) {  // fp32->bf16 RNE
  unsigned u = __builtin_bit_cast(unsigned, f);
  u += 0x7FFFu + ((u >> 16) & 1u);
  return (unsigned short)(u >> 16);
}

__device__ __forceinline__ unsigned pkrelu(float a, float b) {
  a = __builtin_fmaxf(a, 0.f);
  b = __builtin_fmaxf(b, 0.f);
#if __has_builtin(__builtin_amdgcn_cvt_pk_bf16_f32)
  auto h = __builtin_amdgcn_cvt_pk_bf16_f32(a, b);
  return __builtin_bit_cast(unsigned, h);
#else
  // round-half-away bf16: same 0.5-ulp bound as RNE (ties are measure-zero)
  unsigned ia = __builtin_bit_cast(unsigned, a) + 0x8000u;
  unsigned ib = __builtin_bit_cast(unsigned, b) + 0x8000u;
#if __has_builtin(__builtin_amdgcn_perm)
  return __builtin_amdgcn_perm(ib, ia, 0x07060302u);  // (ia.hi16, ib.hi16)
#else
  return (ia >> 16) | (ib & 0xFFFF0000u);
#endif
#endif
}

__device__ __forceinline__ short8 pack4(const f32x4& a0, const f32x4& a1) {
  u32x4 u;
  u.x = pkrelu(a0.x, a0.y);
  u.y = pkrelu(a0.z, a0.w);
  u.z = pkrelu(a1.x, a1.y);
  u.w = pkrelu(a1.z, a1.w);
  return __builtin_bit_cast(short8, u);
}

// consumer B k-slot kp <- producer neuron slot sig_inv(kp)
__device__ __forceinline__ int sig_inv(int kp) {
  return ((kp >> 5) << 5) + (((kp >> 2) & 1) << 4) + (((kp >> 3) & 3) << 2) + (kp & 3);
}

__global__ void nerf_stage(const float* __restrict__ W1, const float* __restrict__ b1,
                           const float* __restrict__ W2, const float* __restrict__ b2,
                           const float* __restrict__ W3, const float* __restrict__ b3,
                           const float* __restrict__ W4, const float* __restrict__ b4,
                           void* __restrict__ ws) {
  unsigned short* wf = (unsigned short*)ws;
  const int idx = blockIdx.x * 256 + threadIdx.x;
  const int stride = gridDim.x * 256;

  // W2 (f 0..31) and W3 (f 32..63) full frags
  for (int p = idx; p < 64 * 64; p += stride) {
    const int f = p >> 6, l = p & 63, m = l & 15, q = l >> 4;
    const int g = f & 31, ks = g >> 3, nt = g & 7;
    const float* W = (f < 32) ? W2 : W3;
    unsigned short v[8];
#pragma unroll
    for (int j = 0; j < 8; ++j)
      v[j] = bfr(W[(nt * 16 + m) * 128 + sig_inv(ks * 32 + q * 8 + j)]);
#pragma unroll
    for (int j = 0; j < 8; ++j) wf[f * 512 + l * 8 + j] = v[j];
  }

  // L1 compact: 8 frags x 16 slots at byte 65536
  for (int e = idx; e < 128; e += stride) {
    const int nt = e >> 4, n = e & 15;
    unsigned short v[8];
#pragma unroll
    for (int j = 0; j < 8; ++j) {
      float val = 0.f;
      if (j < 6) val = W1[(nt * 16 + n) * 6 + j];
      else if (j == 6) val = b1[nt * 16 + n];
      v[j] = bfr(val);
    }
#pragma unroll
    for (int j = 0; j < 8; ++j) wf[(65536 >> 1) + e * 8 + j] = v[j];
  }

  // L4 compact: 4 frags x 16 slots (s = q*4 + outrow) at byte 67584
  for (int e = idx; e < 64; e += stride) {
    const int ks = e >> 4, s = e & 15, q = s >> 2, n = s & 3;
    unsigned short v[8];
#pragma unroll
    for (int j = 0; j < 8; ++j)
      v[j] = bfr(W4[n * 128 + sig_inv(ks * 32 + q * 8 + j)]);
#pragma unroll
    for (int j = 0; j < 8; ++j) wf[(67584 >> 1) + e * 8 + j] = v[j];
  }

  // zeros at byte 68608 (ws is poisoned 0xAA each launch -> must clear)
  {
    float* z = (float*)((char*)ws + 68608);
    for (int e = idx; e < 512; e += stride) z[e] = 0.f;
  }

  // biases at byte 70656: b2 | b3 | b4 padded
  {
    float* wb = (float*)((char*)ws + 70656);
    for (int e = idx; e < 272; e += stride) {
      float val;
      if (e < 128) val = b2[e];
      else if (e < 256) val = b3[e - 128];
      else val = ((e & 15) < 4) ? b4[e & 3] : 0.f;
      wb[e] = val;
    }
  }
}

__launch_bounds__(256)
__global__ void nerf_main(const float* __restrict__ x, float* __restrict__ out,
                          const void* __restrict__ ws, int nGroups) {
  __shared__ __align__(16) unsigned short lds[35872];  // 71744 B

  {  // copy the whole constant slab: 71744/16 = 4484 16B chunks
    const u32x4* src = (const u32x4*)ws;
    u32x4* dst = (u32x4*)lds;
    for (int i = threadIdx.x; i < 4484; i += 256) dst[i] = src[i];
  }
  __syncthreads();

  const int lane = threadIdx.x & 63;
  const int wid = threadIdx.x >> 6;
  const int q = lane >> 4;
  const int n = lane & 15;

  const int waveId = blockIdx.x * 4 + wid;
  const int totalWaves = gridDim.x * 4;

  // lane-conditional bases (computed once; frag index goes in the imm offset)
  const unsigned short* w2b = lds + lane * 8;            // + (ks*8+nt)*512
  const unsigned short* w3b = lds + 16384 + lane * 8;    // + (ks*8+nt)*512
  const unsigned short* l1b =
      lds + (((q == 0) ? 65536 : 68608) >> 1) + n * 8;   // + nt*128
  const unsigned short* l4b =
      lds + (((n < 4) ? (67584 + (q * 4 + n) * 16) : (68608 + n * 16)) >> 1);  // + ks*128
  const f32x4* bias2 = (const f32x4*)((const char*)lds + 70656) + q;  // + nt*4
  const f32x4* bias3 = (const f32x4*)((const char*)lds + 71168) + q;  // + nt*4
  const f32x4* b4p   = (const f32x4*)((const char*)lds + 71680) + q;

  const f32x4 zf = {0.f, 0.f, 0.f, 0.f};

  float px[2][6] = {};
  int g = waveId;
  if (g < nGroups && q == 0) {
#pragma unroll
    for (int t = 0; t < 2; ++t) {
      const float* p = x + (g * 32 + t * 16 + n) * 6;
      f32x2 a = *(const f32x2*)p, b = *(const f32x2*)(p + 2), c = *(const f32x2*)(p + 4);
      px[t][0] = a.x; px[t][1] = a.y; px[t][2] = b.x;
      px[t][3] = b.y; px[t][4] = c.x; px[t][5] = c.y;
    }
  }

  for (; g < nGroups; g += totalWaves) {
    // ---- x -> layer-1 B frags (q==0: k0..5 = x, k6 = 1.0 bias slot) ----
    short8 xb[2];
#pragma unroll
    for (int t = 0; t < 2; ++t) {
      short8 v = {0, 0, 0, 0, 0, 0, 0, 0};
      if (q == 0) {
        v[0] = (short)bfr(px[t][0]); v[1] = (short)bfr(px[t][1]);
        v[2] = (short)bfr(px[t][2]); v[3] = (short)bfr(px[t][3]);
        v[4] = (short)bfr(px[t][4]); v[5] = (short)bfr(px[t][5]);
        v[6] = (short)0x3F80;  // bf16 1.0
      }
      xb[t] = v;
    }
    const int gn = g + totalWaves;
    if (gn < nGroups && q == 0) {
#pragma unroll
      for (int t = 0; t < 2; ++t) {
        const float* p = x + (gn * 32 + t * 16 + n) * 6;
        f32x2 a = *(const f32x2*)p, b = *(const f32x2*)(p + 2), c = *(const f32x2*)(p + 4);
        px[t][0] = a.x; px[t][1] = a.y; px[t][2] = b.x;
        px[t][3] = b.y; px[t][4] = c.x; px[t][5] = c.y;
      }
    }

    short8 B1[2][4], B2[2][4];

    // ---- layer 1 (compact frags; bias in k-slot 6; C = 0) ----
#pragma unroll
    for (int ntp = 0; ntp < 4; ++ntp) {
      const short8 w0 = *(const short8*)(l1b + (2 * ntp) * 128);
      const short8 w1 = *(const short8*)(l1b + (2 * ntp + 1) * 128);
      f32x4 a0[2], a1[2];
#pragma unroll
      for (int t = 0; t < 2; ++t) {
        a0[t] = MFMA(w0, xb[t], zf);
        a1[t] = MFMA(w1, xb[t], zf);
      }
#pragma unroll
      for (int t = 0; t < 2; ++t) B1[t][ntp] = pack4(a0[t], a1[t]);
    }

    // ---- layer 2 (W2 frags; bias as C at ks==0) ----
#pragma unroll
    for (int ntp = 0; ntp < 4; ++ntp) {
      f32x4 a0[2], a1[2];
#pragma unroll
      for (int ks = 0; ks < 4; ++ks) {
        const short8 w0 = *(const short8*)(w2b + (ks * 8 + 2 * ntp) * 512);
        const short8 w1 = *(const short8*)(w2b + (ks * 8 + 2 * ntp + 1) * 512);
        if (ks == 0) {
          const f32x4 bv0 = bias2[(2 * ntp) * 4];
          const f32x4 bv1 = bias2[(2 * ntp + 1) * 4];
#pragma unroll
          for (int t = 0; t < 2; ++t) {
            a0[t] = MFMA(w0, B1[t][0], bv0);
            a1[t] = MFMA(w1, B1[t][0], bv1);
          }
        } else {
#pragma unroll
          for (int t = 0; t < 2; ++t) {
            a0[t] = MFMA(w0, B1[t][ks], a0[t]);
            a1[t] = MFMA(w1, B1[t][ks], a1[t]);
          }
        }
      }
#pragma unroll
      for (int t = 0; t < 2; ++t) B2[t][ntp] = pack4(a0[t], a1[t]);
    }

    // ---- layer 3 (W3 frags) ----
#pragma unroll
    for (int ntp = 0; ntp < 4; ++ntp) {
      f32x4 a0[2], a1[2];
#pragma unroll
      for (int ks = 0; ks < 4; ++ks) {
        const short8 w0 = *(const short8*)(w3b + (ks * 8 + 2 * ntp) * 512);
        const short8 w1 = *(const short8*)(w3b + (ks * 8 + 2 * ntp + 1) * 512);
        if (ks == 0) {
          const f32x4 bv0 = bias3[(2 * ntp) * 4];
          const f32x4 bv1 = bias3[(2 * ntp + 1) * 4];
#pragma unroll
          for (int t = 0; t < 2; ++t) {
            a0[t] = MFMA(w0, B2[t][0], bv0);
            a1[t] = MFMA(w1, B2[t][0], bv1);
          }
        } else {
#pragma unroll
          for (int t = 0; t < 2; ++t) {
            a0[t] = MFMA(w0, B2[t][ks], a0[t]);
            a1[t] = MFMA(w1, B2[t][ks], a1[t]);
          }
        }
      }
#pragma unroll
      for (int t = 0; t < 2; ++t) B1[t][ntp] = pack4(a0[t], a1[t]);  // reuse B1
    }

    // ---- layer 4 (compact frags; out rows at q==0) ----
    f32x4 o[2];
    {
      const f32x4 bv = b4p[0];
#pragma unroll
      for (int ks = 0; ks < 4; ++ks) {
        const short8 w = *(const short8*)(l4b + ks * 128);
        if (ks == 0) {
#pragma unroll
          for (int t = 0; t < 2; ++t) o[t] = MFMA(w, B1[t][0], bv);
        } else {
#pragma unroll
          for (int t = 0; t < 2; ++t) o[t] = MFMA(w, B1[t][ks], o[t]);
        }
      }
    }
    if (q == 0) {
#pragma unroll
      for (int t = 0; t < 2; ++t)
        *(f32x4*)(out + (g * 32 + t * 16 + n) * 4) = o[t];
    }
  }
}

extern "C" void kernel_launch(void* const* d_in, const int* in_sizes, int n_in,
                              void* d_out, int out_size, void* d_ws, size_t ws_size,
                              hipStream_t stream) {
  const float* x  = (const float*)d_in[0];
  const float* W1 = (const float*)d_in[1];
  const float* b1 = (const float*)d_in[2];
  const float* W2 = (const float*)d_in[3];
  const float* b2 = (const float*)d_in[4];
  const float* W3 = (const float*)d_in[5];
  const float* b3 = (const float*)d_in[6];
  const float* W4 = (const float*)d_in[7];
  const float* b4 = (const float*)d_in[8];
  float* out = (float*)d_out;

  const int N = in_sizes[0] / 6;
  const int nGroups = N / 32;  // 2 tiles of 16 rows per wave-iteration -> 32768

  nerf_stage<<<dim3(4), dim3(256), 0, stream>>>(W1, b1, W2, b2, W3, b3, W4, b4, d_ws);

  // 512 blocks x 4 waves = 2048 waves; 2 blocks/CU (143.5 KB LDS), 16 iters
  nerf_main<<<dim3(512), dim3(256), 0, stream>>>(x, out, d_ws, nGroups);
}